// Round 3
// baseline (1797.664 us; speedup 1.0000x reference)
//
#include <hip/hip_runtime.h>
#include <limits.h>

#define CDIM 256
#define KDIM 8192
#define NROWS 32768
#define THW 8192
#define BN 64      // rows per block
#define BK 128     // codes per chunk
#define CCHUNK 16  // channels per staging step

// ws layout (bytes):
//   [0,      131072)  A[n]  = np-pairwise fp32 sum z_flat[n]^2   (32768 f32)
//   [131072, 163840)  Cq[k] = np-pairwise fp32 sum w[k]^2        (8192 f32)
//   [163840, 294912)  idx_i (32768 i32)
//   [294912, 296960)  loss partials (512 f32)

__device__ __forceinline__ float sq_rn(float a) { return __fmul_rn(a, a); }

// numpy pairwise sum of 128 fp32 squares, AVX512 model:
// 8 zmm accumulators v_j[l] = x[j*16+l], lane-wise tree
// ((v0+v1)+(v2+v3))+((v4+v5)+(v6+v7)), then butterfly reduce lanes ^8,^4,^2,^1.
__device__ float pairwise128_sq(const float* __restrict__ p, int stride) {
    float s[16];
#pragma unroll
    for (int l = 0; l < 16; ++l) {
        const float a0 = sq_rn(p[(l)*stride]);
        const float a1 = sq_rn(p[(16 + l) * stride]);
        const float a2 = sq_rn(p[(32 + l) * stride]);
        const float a3 = sq_rn(p[(48 + l) * stride]);
        const float a4 = sq_rn(p[(64 + l) * stride]);
        const float a5 = sq_rn(p[(80 + l) * stride]);
        const float a6 = sq_rn(p[(96 + l) * stride]);
        const float a7 = sq_rn(p[(112 + l) * stride]);
        s[l] = __fadd_rn(__fadd_rn(__fadd_rn(a0, a1), __fadd_rn(a2, a3)),
                         __fadd_rn(__fadd_rn(a4, a5), __fadd_rn(a6, a7)));
    }
    // butterfly: t[l]=s[l]+s[l+8]; u[l]=t[l]+t[l+4]; p[l]=u[l]+u[l+2]; q=p0+p1
    const float u0 = __fadd_rn(__fadd_rn(s[0], s[8]),  __fadd_rn(s[4], s[12]));
    const float u1 = __fadd_rn(__fadd_rn(s[1], s[9]),  __fadd_rn(s[5], s[13]));
    const float u2 = __fadd_rn(__fadd_rn(s[2], s[10]), __fadd_rn(s[6], s[14]));
    const float u3 = __fadd_rn(__fadd_rn(s[3], s[11]), __fadd_rn(s[7], s[15]));
    return __fadd_rn(__fadd_rn(u0, u2), __fadd_rn(u1, u3));
}

__global__ __launch_bounds__(256) void k_A(const float* __restrict__ z,
                                           float* __restrict__ A) {
    const int n = blockIdx.x * 256 + threadIdx.x;   // row id, coalesced loads
    const float* zp = z + (size_t)(n >> 13) * (CDIM * THW) + (n & (THW - 1));
    const float b0 = pairwise128_sq(zp, THW);
    const float b1 = pairwise128_sq(zp + (size_t)128 * THW, THW);
    A[n] = __fadd_rn(b0, b1);
}

__global__ __launch_bounds__(256) void k_C(const float* __restrict__ w,
                                           float* __restrict__ Cq) {
    const int k = blockIdx.x * 256 + threadIdx.x;
    const float* wp = w + (size_t)k * CDIM;
    Cq[k] = __fadd_rn(pairwise128_sq(wp, 1), pairwise128_sq(wp + 128, 1));
}

// Fused scores GEMM + argmin replicating np fp32:
//   M[n][k]  = single ascending-c fmaf chain (OpenBLAS sgemm model)
//   d[n][k]  = RN(RN(A[n] - 2*M) + Cq[k])
//   argmin ascending k, strict <, ties -> lowest index (np.argmin).
__global__ __launch_bounds__(256, 2) void k_argmin(
    const float* __restrict__ z, const float* __restrict__ w,
    const float* __restrict__ A, const float* __restrict__ Cq,
    float* __restrict__ idx_f, int* __restrict__ idx_i)
{
    __shared__ float zt[CDIM][BN];     // 64 KB resident z tile [c][n]
    __shared__ float wt[CCHUNK][BK];   // 8 KB streaming w tile [c][k]

    const int t = threadIdx.x;
    const int blk = blockIdx.x;
    const int b = (blk * BN) >> 13;
    const int s0 = (blk * BN) & (THW - 1);
    const float* zb = z + (size_t)b * (CDIM * THW) + s0;

    {
        const int lane = t & 15;
        const int c0 = t >> 4;
#pragma unroll
        for (int it = 0; it < 16; ++it) {
            const int c = c0 + it * 16;
            float4 v = *reinterpret_cast<const float4*>(zb + (size_t)c * THW + lane * 4);
            *reinterpret_cast<float4*>(&zt[c][lane * 4]) = v;
        }
    }

    const int tcol = t & 15;   // code group: k = kc*BK + tcol*8 + j
    const int trow = t >> 4;   // row group:  n = blk*BN + trow*4 + r

    float Areg[4];
#pragma unroll
    for (int r = 0; r < 4; ++r) Areg[r] = A[blk * BN + trow * 4 + r];

    float best[4];
    int bidx[4];
#pragma unroll
    for (int r = 0; r < 4; ++r) { best[r] = 3.0e38f; bidx[r] = INT_MAX; }

    for (int kc = 0; kc < KDIM / BK; ++kc) {
        float acc[4][8];
#pragma unroll
        for (int r = 0; r < 4; ++r)
#pragma unroll
            for (int j = 0; j < 8; ++j) acc[r][j] = 0.f;

        for (int cc = 0; cc < CDIM / CCHUNK; ++cc) {
            __syncthreads();   // prior compute done reading wt (also fences z load)
            {
                const int kl = t >> 2;
                const int cg = (t & 3) * 4;
#pragma unroll
                for (int p = 0; p < 2; ++p) {
                    const int kk = kl + p * 64;
                    float4 v = *reinterpret_cast<const float4*>(
                        w + (size_t)(kc * BK + kk) * CDIM + cc * CCHUNK + cg);
                    wt[cg + 0][kk] = v.x;
                    wt[cg + 1][kk] = v.y;
                    wt[cg + 2][kk] = v.z;
                    wt[cg + 3][kk] = v.w;
                }
            }
            __syncthreads();
            // single fmaf chain per (r,j), c strictly ascending 0..255
#pragma unroll
            for (int c = 0; c < CCHUNK; ++c) {
                const float4 zv = *reinterpret_cast<const float4*>(&zt[cc * CCHUNK + c][trow * 4]);
                const float4 w0 = *reinterpret_cast<const float4*>(&wt[c][tcol * 8]);
                const float4 w1 = *reinterpret_cast<const float4*>(&wt[c][tcol * 8 + 4]);
                const float zr[4] = {zv.x, zv.y, zv.z, zv.w};
                const float wr[8] = {w0.x, w0.y, w0.z, w0.w, w1.x, w1.y, w1.z, w1.w};
#pragma unroll
                for (int r = 0; r < 4; ++r)
#pragma unroll
                    for (int j = 0; j < 8; ++j)
                        acc[r][j] = fmaf(zr[r], wr[j], acc[r][j]);
            }
        }
        const float4 c0 = *reinterpret_cast<const float4*>(Cq + kc * BK + tcol * 8);
        const float4 c1 = *reinterpret_cast<const float4*>(Cq + kc * BK + tcol * 8 + 4);
        const float cv[8] = {c0.x, c0.y, c0.z, c0.w, c1.x, c1.y, c1.z, c1.w};
#pragma unroll
        for (int j = 0; j < 8; ++j) {
            const int kg = kc * BK + tcol * 8 + j;
#pragma unroll
            for (int r = 0; r < 4; ++r) {
                // d = RN(RN(A - 2M) + C); 2*M and negation are exact
                const float dd = __fadd_rn(__fadd_rn(Areg[r], -2.0f * acc[r][j]), cv[j]);
                if (dd < best[r]) { best[r] = dd; bidx[r] = kg; }
            }
        }
    }

    // Merge across the 16 code-groups; ties -> lower global index.
#pragma unroll
    for (int m = 1; m < 16; m <<= 1) {
#pragma unroll
        for (int r = 0; r < 4; ++r) {
            const float od = __shfl_xor(best[r], m, 64);
            const int oi = __shfl_xor(bidx[r], m, 64);
            if (od < best[r] || (od == best[r] && oi < bidx[r])) {
                best[r] = od; bidx[r] = oi;
            }
        }
    }
    if (tcol == 0) {
#pragma unroll
        for (int r = 0; r < 4; ++r) {
            const int n = blk * BN + trow * 4 + r;
            idx_f[n] = (float)bidx[r];
            idx_i[n] = bidx[r];
        }
    }
}

// Gather z_q = w[idx], transpose to [B,C,T,H,W], accumulate sum((z_q - z)^2).
__global__ __launch_bounds__(256, 2) void k_out(
    const float* __restrict__ w, const float* __restrict__ z,
    const int* __restrict__ idx, float* __restrict__ out0,
    float* __restrict__ partial)
{
    __shared__ float q[CDIM][BN + 1];
    __shared__ int si[BN];
    __shared__ float red[256];

    const int t = threadIdx.x;
    const int blk = blockIdx.x;
    const int n0 = blk * BN;
    const int b = n0 >> 13;
    const int s0 = n0 & (THW - 1);

    if (t < BN) si[t] = idx[n0 + t];
    __syncthreads();

    {
        const int c = t;
#pragma unroll 4
        for (int i = 0; i < BN; ++i)
            q[c][i] = w[(size_t)si[i] * CDIM + c];
    }
    __syncthreads();

    const int sl = t & 63;
    const int cb = t >> 6;
    float lacc = 0.f;
    const size_t base = (size_t)b * (CDIM * THW) + s0 + sl;
#pragma unroll 4
    for (int j = 0; j < 64; ++j) {
        const int c = cb * 64 + j;
        const float qv = q[c][sl];
        const size_t a = base + (size_t)c * THW;
        const float zv = z[a];
        out0[a] = qv;
        const float d = qv - zv;
        lacc = fmaf(d, d, lacc);
    }
    red[t] = lacc;
    __syncthreads();
    for (int mm = 128; mm > 0; mm >>= 1) {
        if (t < mm) red[t] += red[t + mm];
        __syncthreads();
    }
    if (t == 0) partial[blk] = red[0];
}

__global__ __launch_bounds__(256) void k_loss(const float* __restrict__ partial,
                                              float* __restrict__ out_loss) {
    __shared__ double red[256];
    const int t = threadIdx.x;
    double a = 0.0;
    for (int i = t; i < NROWS / BN; i += 256) a += (double)partial[i];
    red[t] = a;
    __syncthreads();
    for (int mm = 128; mm > 0; mm >>= 1) {
        if (t < mm) red[t] += red[t + mm];
        __syncthreads();
    }
    if (t == 0) out_loss[0] = (float)(1.25 * red[0] / 8388608.0);
}

extern "C" void kernel_launch(void* const* d_in, const int* in_sizes, int n_in,
                              void* d_out, int out_size, void* d_ws, size_t ws_size,
                              hipStream_t stream) {
    const float* z = (const float*)d_in[0];
    const float* w = (const float*)d_in[1];
    float* out = (float*)d_out;

    char* ws = (char*)d_ws;
    float* A = (float*)ws;                    // 131072 B
    float* Cq = (float*)(ws + 131072);        // 32768 B
    int* idxi = (int*)(ws + 163840);          // 131072 B
    float* partial = (float*)(ws + 294912);   // 2048 B

    float* out_zq = out;                 // [B,C,T,H,W] = 8388608
    float* out_loss = out + 8388608;     // scalar
    float* out_idx = out + 8388609;      // [B,T,H,W] = 32768, as float

    k_A<<<NROWS / 256, 256, 0, stream>>>(z, A);
    k_C<<<KDIM / 256, 256, 0, stream>>>(w, Cq);
    k_argmin<<<NROWS / BN, 256, 0, stream>>>(z, w, A, Cq, out_idx, idxi);
    k_out<<<NROWS / BN, 256, 0, stream>>>(w, z, idxi, out_zq, partial);
    k_loss<<<1, 256, 0, stream>>>(partial, out_loss);
}